// Round 16
// baseline (142.476 us; speedup 1.0000x reference)
//
#include <hip/hip_runtime.h>
#include <hip/hip_bf16.h>
#include <stdint.h>

typedef __attribute__((ext_vector_type(8))) __bf16 bf16x8;
typedef __attribute__((ext_vector_type(4))) float  f32x4;
typedef __attribute__((ext_vector_type(2))) unsigned int u32x2;

#define S_  2048
#define D_  128
#define QB  64          // q rows per block: 2 waves x 32 (4 blocks/CU)
#define KB  32          // kv rows per tile
#define NT  (S_/KB)     // 64 tiles
#define VPANEL 1056     // V panel stride bytes (1024 data + 32 pad)
#define VBUF   (8*VPANEL)

__device__ __forceinline__ __bf16 f2bf(float f){ return (__bf16)f; }

__device__ __forceinline__ bf16x8 pack8(float4 a, float4 b){
  bf16x8 r;
  r[0]=f2bf(a.x); r[1]=f2bf(a.y); r[2]=f2bf(a.z); r[3]=f2bf(a.w);
  r[4]=f2bf(b.x); r[5]=f2bf(b.y); r[6]=f2bf(b.z); r[7]=f2bf(b.w);
  return r;
}

__global__ __launch_bounds__(128, 2)
void attn_fwd(const float* __restrict__ Q, const float* __restrict__ K,
              const float* __restrict__ V, float* __restrict__ O) {
  // K: row-major, rows padded to 136 elems (272B stride) — proven layout
  __shared__ __align__(128) __bf16 k_lds[2][KB][136];
  // V: 8 panels of [32 kk][16 d], stride 1056B; half-rows parity-swapped — proven
  __shared__ __align__(128) unsigned char v_raw[2][VBUF];

  const int t   = threadIdx.x;
  const int w   = t >> 6;        // wave 0/1
  const int l   = t & 63;
  const int l16 = l & 15;
  const int lg  = l >> 4;

  // XCD-aware remap: all 32 q-blocks of a batch land on one XCD
  const int f  = blockIdx.x;                    // 0..1023
  const int b  = ((f & 7) << 2) | ((f >> 3) & 3);
  const int bq = f >> 5;                        // 0..31

  const float* Qb = Q + (size_t)b * (S_*D_);
  const float* Kb = K + (size_t)b * (S_*D_);
  const float* Vb = V + (size_t)b * (S_*D_);
  float*       Ob = O + (size_t)b * (S_*D_);

  const int q0 = bq*QB + w*32;
  // fold 1/sqrt(128) * log2(e) into Q so P = exp(S/sqrt(d)) = 2^(S*qscale)
  const float qscale = 0.08838834764831845f * 1.4426950408889634f;

  // ---- Q fragments (B-operand: col q = l16, slot j <-> k = (j>>2)*16 + 4*lg + (j&3))
  bf16x8 qf[2][4];
  #pragma unroll
  for (int qt=0; qt<2; ++qt){
    const float* qr = Qb + (size_t)(q0 + qt*16 + l16) * D_;
    #pragma unroll
    for (int ds=0; ds<4; ++ds){
      const float4* p = (const float4*)(qr + ds*32 + lg*8);
      float4 a = p[0], c = p[1];
      a.x*=qscale; a.y*=qscale; a.z*=qscale; a.w*=qscale;
      c.x*=qscale; c.y*=qscale; c.z*=qscale; c.w*=qscale;
      qf[qt][ds] = pack8(a, c);
    }
  }

  f32x4 acc[2][8];
  #pragma unroll
  for (int qt=0; qt<2; ++qt)
    #pragma unroll
    for (int dt=0; dt<8; ++dt)
      acc[qt][dt] = (f32x4){0.f,0.f,0.f,0.f};
  float den0 = 0.f, den1 = 0.f;

  // ---- staging: 128 threads -> rows {sr, sr+16}, 16-float d-chunk sdt (R7-proven)
  const int sr  = t >> 3;        // 0..15
  const int sdt = t & 7;         // panel / d-chunk 0..7
  const int par = sdt & 1;       // half-row parity swizzle key
  const float* Kst = Kb + (size_t)sr * D_ + sdt*16;
  const float* Vst = Vb + (size_t)sr * D_ + sdt*16;

  float4 ksa0,ksa1,ksa2,ksa3, ksb0,ksb1,ksb2,ksb3;
  float4 vsa0,vsa1,vsa2,vsa3, vsb0,vsb1,vsb2,vsb3;

  #define LOADT(IT) do { \
    const float4* ka_ = (const float4*)(Kst + (size_t)(IT)*KB*D_); \
    const float4* kb_ = (const float4*)(Kst + (size_t)(IT)*KB*D_ + 16*D_); \
    const float4* va_ = (const float4*)(Vst + (size_t)(IT)*KB*D_); \
    const float4* vb2_ = (const float4*)(Vst + (size_t)(IT)*KB*D_ + 16*D_); \
    ksa0=ka_[0]; ksa1=ka_[1]; ksa2=ka_[2]; ksa3=ka_[3]; \
    ksb0=kb_[0]; ksb1=kb_[1]; ksb2=kb_[2]; ksb3=kb_[3]; \
    vsa0=va_[0]; vsa1=va_[1]; vsa2=va_[2]; vsa3=va_[3]; \
    vsb0=vb2_[0]; vsb1=vb2_[1]; vsb2=vb2_[2]; vsb3=vb2_[3]; \
  } while(0)

  #define WRITET(BUF) do { \
    *(bf16x8*)&k_lds[BUF][sr][sdt*16    ]     = pack8(ksa0,ksa1); \
    *(bf16x8*)&k_lds[BUF][sr][sdt*16 + 8]     = pack8(ksa2,ksa3); \
    *(bf16x8*)&k_lds[BUF][sr+16][sdt*16    ]  = pack8(ksb0,ksb1); \
    *(bf16x8*)&k_lds[BUF][sr+16][sdt*16 + 8]  = pack8(ksb2,ksb3); \
    unsigned char* va_p = &v_raw[BUF][sdt*VPANEL + sr*32]; \
    *(bf16x8*)(va_p + (par<<4))          = pack8(vsa0,vsa1); \
    *(bf16x8*)(va_p + ((par^1)<<4))      = pack8(vsa2,vsa3); \
    unsigned char* vb_p = va_p + 16*32; \
    *(bf16x8*)(vb_p + (par<<4))          = pack8(vsb0,vsb1); \
    *(bf16x8*)(vb_p + ((par^1)<<4))      = pack8(vsb2,vsb3); \
  } while(0)

  // tr-read addressing — proven round-4 formulas
  const unsigned vbase   = (unsigned)(uintptr_t)&v_raw[0][0];
  const unsigned troff_e = (unsigned)(lg*128 + (l16>>2)*32 + ((l16&3)*8));
  const unsigned troff_o = (unsigned)(lg*128 + (l16>>2)*32 + (((l16&3)*8) ^ 16));

  // pipeline registers: V frags + P frags of tile t, consumed by PV one iter later
  u32x2 vlo[8], vhi[8];
  bf16x8 pf[2];

  // ---- phase macros (byte-identical to R12) ----
  #define QK_BLOCK(CUR, SVAR) do { \
    __builtin_amdgcn_s_setprio(1); \
    _Pragma("unroll") \
    for (int ct=0; ct<2; ++ct){ \
      bf16x8 kf[4]; \
      _Pragma("unroll") \
      for (int ds=0; ds<4; ++ds) \
        kf[ds] = *(const bf16x8*)&k_lds[CUR][ct*16 + l16][ds*32 + lg*8]; \
      _Pragma("unroll") \
      for (int qt=0; qt<2; ++qt){ \
        f32x4 sv = (f32x4){0.f,0.f,0.f,0.f}; \
        _Pragma("unroll") \
        for (int ds=0; ds<4; ++ds) \
          sv = __builtin_amdgcn_mfma_f32_16x16x32_bf16(kf[ds], qf[qt][ds], sv, 0,0,0); \
        SVAR[qt][ct] = sv; \
      } \
    } \
    __builtin_amdgcn_s_setprio(0); \
  } while(0)

  #define PV_BLOCK() do { \
    __builtin_amdgcn_s_setprio(1); \
    _Pragma("unroll") \
    for (int dt=0; dt<8; ++dt){ \
      union { bf16x8 v; u32x2 u[2]; } uu; \
      uu.u[0] = vlo[dt]; uu.u[1] = vhi[dt]; \
      acc[0][dt] = __builtin_amdgcn_mfma_f32_16x16x32_bf16(uu.v, pf[0], acc[0][dt], 0,0,0); \
      acc[1][dt] = __builtin_amdgcn_mfma_f32_16x16x32_bf16(uu.v, pf[1], acc[1][dt], 0,0,0); \
    } \
    __builtin_amdgcn_s_setprio(0); \
  } while(0)

  #define EXP_BLOCK(SVAR) do { \
    _Pragma("unroll") \
    for (int qt=0; qt<2; ++qt){ \
      float dsum = 0.f; \
      _Pragma("unroll") \
      for (int ct=0; ct<2; ++ct){ \
        _Pragma("unroll") \
        for (int r=0; r<4; ++r){ \
          float e = __builtin_amdgcn_exp2f(SVAR[qt][ct][r]); \
          dsum += e; \
          pf[qt][ct*4+r] = f2bf(e); \
        } \
      } \
      if (qt==0) den0 += dsum; else den1 += dsum; \
    } \
  } while(0)

  #define TR_ISSUE(CUR) do { \
    const unsigned vb_e = vbase + (unsigned)((CUR)*VBUF) + troff_e; \
    const unsigned vb_o = vbase + (unsigned)((CUR)*VBUF) + troff_o; \
    _Pragma("unroll") \
    for (int dt=0; dt<8; ++dt){ \
      const unsigned a = ((dt & 1) ? vb_o : vb_e) + (unsigned)(dt*VPANEL); \
      asm volatile("ds_read_b64_tr_b16 %0, %2\n\t" \
                   "ds_read_b64_tr_b16 %1, %2 offset:512" \
                   : "=&v"(vlo[dt]), "=&v"(vhi[dt]) \
                   : "v"(a)); \
    } \
  } while(0)

  #define FENCE() do { \
    asm volatile("s_waitcnt lgkmcnt(0)" ::: "memory"); \
    __builtin_amdgcn_sched_barrier(0); \
    __syncthreads(); \
  } while(0)

  // ---- prologue: buf0 <- tile0; regs <- tile1
  LOADT(0); WRITET(0); LOADT(1);
  __syncthreads();

  // ---- peeled iteration 0 (R12-proven schedule)
  {
    TR_ISSUE(0);
    WRITET(1);
    LOADT(2);
    f32x4 s0[2][2];
    QK_BLOCK(0, s0);
    EXP_BLOCK(s0);
    FENCE();
  }

  // ---- main loop: PV(t-1); tr-issue(t); staging; QK(t); exp(t); fence
  for (int it = 1; it < NT; ++it){
    const int cur = it & 1;

    PV_BLOCK();
    TR_ISSUE(cur);
    if (it+1 < NT) WRITET(cur^1);
    if (it+2 < NT) LOADT(it+2);

    f32x4 s[2][2];
    QK_BLOCK(cur, s);
    EXP_BLOCK(s);
    FENCE();
  }

  // ---- epilogue: PV for tile NT-1
  PV_BLOCK();

  // ---- finalize: reduce den over lane groups, divide, coalesced float4 stores
  #pragma unroll
  for (int qt=0; qt<2; ++qt){
    float dsum = (qt==0) ? den0 : den1;
    dsum += __shfl_xor(dsum, 16);
    dsum += __shfl_xor(dsum, 32);
    const float inv = 1.0f / dsum;
    float* orow = Ob + (size_t)(q0 + qt*16 + l16) * D_ + lg*4;
    #pragma unroll
    for (int dt=0; dt<8; ++dt){
      f32x4 a4 = acc[qt][dt];
      float4 o4;
      o4.x = a4[0]*inv; o4.y = a4[1]*inv; o4.z = a4[2]*inv; o4.w = a4[3]*inv;
      *(float4*)(orow + dt*16) = o4;
    }
  }
}

extern "C" void kernel_launch(void* const* d_in, const int* in_sizes, int n_in,
                              void* d_out, int out_size, void* d_ws, size_t ws_size,
                              hipStream_t stream) {
  const float* q = (const float*)d_in[0];
  const float* k = (const float*)d_in[1];
  const float* v = (const float*)d_in[2];
  float* o = (float*)d_out;
  attn_fwd<<<dim3(1024), dim3(128), 0, stream>>>(q, k, v, o);
}

// Round 17
// 90.088 us; speedup vs baseline: 1.5815x; 1.5815x over previous
//
#include <hip/hip_runtime.h>
#include <hip/hip_bf16.h>
#include <stdint.h>

typedef __attribute__((ext_vector_type(8))) __bf16 bf16x8;
typedef __attribute__((ext_vector_type(4))) float  f32x4;
typedef __attribute__((ext_vector_type(2))) unsigned int u32x2;

#define S_  2048
#define D_  128
#define QB  128         // q rows per block: 4 waves x 32
#define KB  32          // kv rows per tile
#define NT  (S_/KB)     // 64 tiles
#define VPANEL 1056     // V panel stride bytes (1024 data + 32 pad)
#define VBUF   (8*VPANEL)

__device__ __forceinline__ __bf16 f2bf(float f){ return (__bf16)f; }

__device__ __forceinline__ bf16x8 pack8(float4 a, float4 b){
  bf16x8 r;
  r[0]=f2bf(a.x); r[1]=f2bf(a.y); r[2]=f2bf(a.z); r[3]=f2bf(a.w);
  r[4]=f2bf(b.x); r[5]=f2bf(b.y); r[6]=f2bf(b.z); r[7]=f2bf(b.w);
  return r;
}

__global__ __launch_bounds__(256, 2)
void attn_fwd(const float* __restrict__ Q, const float* __restrict__ K,
              const float* __restrict__ V, float* __restrict__ O) {
  // K: row-major, rows padded to 136 elems (272B stride) — proven layout
  __shared__ __align__(128) __bf16 k_lds[2][KB][136];
  // V: 8 panels of [32 kk][16 d], stride 1056B; half-rows parity-swapped — proven
  __shared__ __align__(128) unsigned char v_raw[2][VBUF];

  const int t   = threadIdx.x;
  const int w   = t >> 6;
  const int l   = t & 63;
  const int l16 = l & 15;
  const int lg  = l >> 4;

  // XCD-aware remap: 16 q-blocks of each batch land on one XCD
  const int f  = blockIdx.x;
  const int b  = ((f & 7) << 2) | ((f >> 3) & 3);
  const int bq = f >> 5;

  const float* Qb = Q + (size_t)b * (S_*D_);
  const float* Kb = K + (size_t)b * (S_*D_);
  const float* Vb = V + (size_t)b * (S_*D_);
  float*       Ob = O + (size_t)b * (S_*D_);

  const int q0 = bq*QB + w*32;
  // fold 1/sqrt(128) * log2(e) into Q so P = exp(S/sqrt(d)) = 2^(S*qscale)
  const float qscale = 0.08838834764831845f * 1.4426950408889634f;

  // ---- Q fragments (B-operand: col q = l16, slot j <-> k = (j>>2)*16 + 4*lg + (j&3))
  bf16x8 qf[2][4];
  #pragma unroll
  for (int qt=0; qt<2; ++qt){
    const float* qr = Qb + (size_t)(q0 + qt*16 + l16) * D_;
    #pragma unroll
    for (int ds=0; ds<4; ++ds){
      const float4* p = (const float4*)(qr + ds*32 + lg*8);
      float4 a = p[0], c = p[1];
      a.x*=qscale; a.y*=qscale; a.z*=qscale; a.w*=qscale;
      c.x*=qscale; c.y*=qscale; c.z*=qscale; c.w*=qscale;
      qf[qt][ds] = pack8(a, c);
    }
  }

  f32x4 acc[2][8];
  #pragma unroll
  for (int qt=0; qt<2; ++qt)
    #pragma unroll
    for (int dt=0; dt<8; ++dt)
      acc[qt][dt] = (f32x4){0.f,0.f,0.f,0.f};
  float den0 = 0.f, den1 = 0.f;

  // ---- staging: thread -> (row sr, 16-float d-chunk sdt)
  const int sr  = t >> 3;        // 0..31
  const int sdt = t & 7;         // panel / d-chunk 0..7
  const int par = sdt & 1;       // half-row parity swizzle key
  const float* Kst = Kb + (size_t)sr * D_ + sdt*16;
  const float* Vst = Vb + (size_t)sr * D_ + sdt*16;

  float4 kst0,kst1,kst2,kst3, vst0,vst1,vst2,vst3;

  #define LOADT(IT) do { \
    const float4* kp_ = (const float4*)(Kst + (size_t)(IT)*KB*D_); \
    const float4* vp_ = (const float4*)(Vst + (size_t)(IT)*KB*D_); \
    kst0=kp_[0]; kst1=kp_[1]; kst2=kp_[2]; kst3=kp_[3]; \
    vst0=vp_[0]; vst1=vp_[1]; vst2=vp_[2]; vst3=vp_[3]; \
  } while(0)

  #define WRITET(BUF) do { \
    *(bf16x8*)&k_lds[BUF][sr][sdt*16    ] = pack8(kst0,kst1); \
    *(bf16x8*)&k_lds[BUF][sr][sdt*16 + 8] = pack8(kst2,kst3); \
    unsigned char* vb_ = &v_raw[BUF][sdt*VPANEL + sr*32]; \
    *(bf16x8*)(vb_ + (par<<4))        = pack8(vst0,vst1); \
    *(bf16x8*)(vb_ + ((par^1)<<4))    = pack8(vst2,vst3); \
  } while(0)

  // tr-read addressing — proven round-4 formulas
  const unsigned vbase   = (unsigned)(uintptr_t)&v_raw[0][0];
  const unsigned troff_e = (unsigned)(lg*128 + (l16>>2)*32 + ((l16&3)*8));
  const unsigned troff_o = (unsigned)(lg*128 + (l16>>2)*32 + (((l16&3)*8) ^ 16));

  // pipeline registers: V frags + P frags of tile t, consumed by PV one iter later
  u32x2 vlo[8], vhi[8];
  bf16x8 pf[2];

  // ---- phase macros ----
  #define QK_BLOCK(CUR, SVAR) do { \
    __builtin_amdgcn_s_setprio(1); \
    _Pragma("unroll") \
    for (int ct=0; ct<2; ++ct){ \
      bf16x8 kf[4]; \
      _Pragma("unroll") \
      for (int ds=0; ds<4; ++ds) \
        kf[ds] = *(const bf16x8*)&k_lds[CUR][ct*16 + l16][ds*32 + lg*8]; \
      _Pragma("unroll") \
      for (int qt=0; qt<2; ++qt){ \
        f32x4 sv = (f32x4){0.f,0.f,0.f,0.f}; \
        _Pragma("unroll") \
        for (int ds=0; ds<4; ++ds) \
          sv = __builtin_amdgcn_mfma_f32_16x16x32_bf16(kf[ds], qf[qt][ds], sv, 0,0,0); \
        SVAR[qt][ct] = sv; \
      } \
    } \
    __builtin_amdgcn_s_setprio(0); \
  } while(0)

  #define PV_BLOCK() do { \
    __builtin_amdgcn_s_setprio(1); \
    _Pragma("unroll") \
    for (int dt=0; dt<8; ++dt){ \
      union { bf16x8 v; u32x2 u[2]; } uu; \
      uu.u[0] = vlo[dt]; uu.u[1] = vhi[dt]; \
      acc[0][dt] = __builtin_amdgcn_mfma_f32_16x16x32_bf16(uu.v, pf[0], acc[0][dt], 0,0,0); \
      acc[1][dt] = __builtin_amdgcn_mfma_f32_16x16x32_bf16(uu.v, pf[1], acc[1][dt], 0,0,0); \
    } \
    __builtin_amdgcn_s_setprio(0); \
  } while(0)

  // P = 2^S with qscale pre-folded; __builtin_amdgcn_exp2f -> v_exp_f32 via the
  // compiler (TRANS hazard handled; round-5 lesson: never raw TRANS asm)
  #define EXP_BLOCK(SVAR) do { \
    _Pragma("unroll") \
    for (int qt=0; qt<2; ++qt){ \
      float dsum = 0.f; \
      _Pragma("unroll") \
      for (int ct=0; ct<2; ++ct){ \
        _Pragma("unroll") \
        for (int r=0; r<4; ++r){ \
          float e = __builtin_amdgcn_exp2f(SVAR[qt][ct][r]); \
          dsum += e; \
          pf[qt][ct*4+r] = f2bf(e); \
        } \
      } \
      if (qt==0) den0 += dsum; else den1 += dsum; \
    } \
  } while(0)

  #define TR_ISSUE(CUR) do { \
    const unsigned vb_e = vbase + (unsigned)((CUR)*VBUF) + troff_e; \
    const unsigned vb_o = vbase + (unsigned)((CUR)*VBUF) + troff_o; \
    _Pragma("unroll") \
    for (int dt=0; dt<8; ++dt){ \
      const unsigned a = ((dt & 1) ? vb_o : vb_e) + (unsigned)(dt*VPANEL); \
      asm volatile("ds_read_b64_tr_b16 %0, %2\n\t" \
                   "ds_read_b64_tr_b16 %1, %2 offset:512" \
                   : "=&v"(vlo[dt]), "=&v"(vhi[dt]) \
                   : "v"(a)); \
    } \
  } while(0)

  #define FENCE() do { \
    asm volatile("s_waitcnt lgkmcnt(0)" ::: "memory"); \
    __builtin_amdgcn_sched_barrier(0); \
    __syncthreads(); \
  } while(0)

  // ---- prologue: buf0 <- tile0; regs <- tile1
  LOADT(0); WRITET(0); LOADT(1);
  __syncthreads();

  // ---- peeled iteration 0 (no PV yet): tr-issue(0) early -> QK(0) -> exp
  {
    TR_ISSUE(0);               // buf0 fenced by prologue barrier; full iter to drain
    WRITET(1);                 // tile 1 -> buf 1
    LOADT(2);
    f32x4 s0[2][2];
    QK_BLOCK(0, s0);
    EXP_BLOCK(s0);
    FENCE();
  }

  // ---- main loop (round-9 proven schedule): PV(t-1) first; tr-issue(t) right
  //      after (whole iter to drain); then staging + QK(t) + exp(t).
  for (int it = 1; it < NT; ++it){
    const int cur = it & 1;

    PV_BLOCK();                // consumes old vlo/vhi + pf before refill (WAR safe)
    TR_ISSUE(cur);             // refill vlo/vhi for tile it; src buf fenced last iter
    if (it+1 < NT) WRITET(cur^1);
    if (it+2 < NT) LOADT(it+2);

    f32x4 s[2][2];
    QK_BLOCK(cur, s);
    EXP_BLOCK(s);              // refills pf for tile it
    FENCE();                   // tr reads long done -> lgkmcnt(0) ~free
  }

  // ---- epilogue: PV for tile NT-1
  PV_BLOCK();

  // ---- finalize: reduce den over lane groups, divide, coalesced float4 stores
  #pragma unroll
  for (int qt=0; qt<2; ++qt){
    float dsum = (qt==0) ? den0 : den1;
    dsum += __shfl_xor(dsum, 16);
    dsum += __shfl_xor(dsum, 32);
    const float inv = 1.0f / dsum;
    float* orow = Ob + (size_t)(q0 + qt*16 + l16) * D_ + lg*4;
    #pragma unroll
    for (int dt=0; dt<8; ++dt){
      f32x4 a4 = acc[qt][dt];
      float4 o4;
      o4.x = a4[0]*inv; o4.y = a4[1]*inv; o4.z = a4[2]*inv; o4.w = a4[3]*inv;
      *(float4*)(orow + dt*16) = o4;
    }
  }
}

extern "C" void kernel_launch(void* const* d_in, const int* in_sizes, int n_in,
                              void* d_out, int out_size, void* d_ws, size_t ws_size,
                              hipStream_t stream) {
  const float* q = (const float*)d_in[0];
  const float* k = (const float*)d_in[1];
  const float* v = (const float*)d_in[2];
  float* o = (float*)d_out;
  attn_fwd<<<dim3(512), dim3(256), 0, stream>>>(q, k, v, o);
}